// Round 1
// baseline (296.002 us; speedup 1.0000x reference)
//
#include <hip/hip_runtime.h>

typedef unsigned short u16;
typedef __attribute__((ext_vector_type(4))) float f32x4;
typedef __attribute__((ext_vector_type(8))) __bf16 bf16x8;
typedef __attribute__((ext_vector_type(4))) unsigned short u16x4;
typedef __attribute__((ext_vector_type(8))) unsigned short u16x8;

// round-to-nearest-even fp32 -> bf16
static __device__ __forceinline__ u16 f2bf(float f) {
    union { float f; unsigned u; } v; v.f = f;
    unsigned r = v.u + 0x7FFFu + ((v.u >> 16) & 1u);
    return (u16)(r >> 16);
}

// ---------------- fp32 -> bf16 convert (4 elems/thread) ----------------
__global__ __launch_bounds__(256) void k_cvt(const float* __restrict__ in, u16* __restrict__ out) {
    size_t i = (size_t)blockIdx.x * 256 + threadIdx.x;
    float4 v = ((const float4*)in)[i];
    u16x4 o; o[0] = f2bf(v.x); o[1] = f2bf(v.y); o[2] = f2bf(v.z); o[3] = f2bf(v.w);
    *(u16x4*)(out + i * 4) = o;
}

// ---------------- W [K=1024][N=1024] fp32 -> Wt [N][K] bf16 (scaled) ----------------
__global__ __launch_bounds__(256) void k_wtrans(const float* __restrict__ W, u16* __restrict__ Wt, float scale) {
    __shared__ float tile[32][33];
    int n0 = blockIdx.x * 32, k0 = blockIdx.y * 32;
    int tid = threadIdx.x;
    int r = tid >> 3, c = (tid & 7) * 4;
    float4 v = *(const float4*)(W + (size_t)(k0 + r) * 1024 + n0 + c);
    tile[r][c] = v.x; tile[r][c + 1] = v.y; tile[r][c + 2] = v.z; tile[r][c + 3] = v.w;
    __syncthreads();
    u16x4 o;
    o[0] = f2bf(tile[c][r] * scale);
    o[1] = f2bf(tile[c + 1][r] * scale);
    o[2] = f2bf(tile[c + 2][r] * scale);
    o[3] = f2bf(tile[c + 3][r] * scale);
    *(u16x4*)(Wt + (size_t)(n0 + r) * 1024 + k0 + c) = o;
}

// ---------------- per-batch 1024x1024 bf16 transpose: Vb[b*1024+t][n] -> Vt[b*1024+n][t] ----------------
__global__ __launch_bounds__(256) void k_vtrans(const u16* __restrict__ Vb, u16* __restrict__ Vt) {
    __shared__ u16 tile[32][34];
    int z = blockIdx.z;
    int n0 = blockIdx.x * 32, t0 = blockIdx.y * 32;
    int tid = threadIdx.x;
    int r = tid >> 3, c = (tid & 7) * 4;
    u16x4 v = *(const u16x4*)(Vb + ((size_t)(z * 1024 + t0 + r)) * 1024 + n0 + c);
    tile[r][c] = v[0]; tile[r][c + 1] = v[1]; tile[r][c + 2] = v[2]; tile[r][c + 3] = v[3];
    __syncthreads();
    u16x4 o; o[0] = tile[c][r]; o[1] = tile[c + 1][r]; o[2] = tile[c + 2][r]; o[3] = tile[c + 3][r];
    *(u16x4*)(Vt + ((size_t)(z * 1024 + n0 + r)) * 1024 + t0 + c) = o;
}

// ---------------- bf16 GEMM: C[M=8192][N=1024] = A[M][1024] * Bt[N][1024]^T + bias ----------------
// 128x128 tile, BK=32, 4 waves (2x2 of 64x64), 4x4 x (16x16) frags per wave.
__global__ __launch_bounds__(256) void k_gemm(const u16* __restrict__ A, const u16* __restrict__ Bt,
                                              const float* __restrict__ bias, float bias_scale,
                                              u16* __restrict__ obf, float* __restrict__ of32) {
    __shared__ u16 As[128 * 32];
    __shared__ u16 Bs[128 * 32];
    const int tid = threadIdx.x;
    const int l = tid & 63, w = tid >> 6;
    const int wm = (w >> 1) * 64, wn = (w & 1) * 64;
    const size_t m0 = (size_t)blockIdx.y * 128, n0 = (size_t)blockIdx.x * 128;
    const int srow = tid >> 1, scol = (tid & 1) * 16;   // each thread stages 16 elems/matrix
    const u16* Ag = A + (m0 + srow) * 1024 + scol;
    const u16* Bg = Bt + (n0 + srow) * 1024 + scol;
    const int fr = l & 15, f8 = (l >> 4) * 8, f4 = (l >> 4) * 4;
    f32x4 acc[4][4] = {};
    u16x8 av0 = *(const u16x8*)Ag, av1 = *(const u16x8*)(Ag + 8);
    u16x8 bv0 = *(const u16x8*)Bg, bv1 = *(const u16x8*)(Bg + 8);
    for (int kt = 0; kt < 1024; kt += 32) {
        __syncthreads();
        *(u16x8*)(&As[srow * 32 + scol]) = av0;
        *(u16x8*)(&As[srow * 32 + scol + 8]) = av1;
        *(u16x8*)(&Bs[srow * 32 + scol]) = bv0;
        *(u16x8*)(&Bs[srow * 32 + scol + 8]) = bv1;
        __syncthreads();
        if (kt + 32 < 1024) {   // prefetch next K-tile during compute
            av0 = *(const u16x8*)(Ag + kt + 32); av1 = *(const u16x8*)(Ag + kt + 40);
            bv0 = *(const u16x8*)(Bg + kt + 32); bv1 = *(const u16x8*)(Bg + kt + 40);
        }
        bf16x8 af[4], bf[4];
#pragma unroll
        for (int mt = 0; mt < 4; ++mt) af[mt] = *(const bf16x8*)(&As[(wm + mt * 16 + fr) * 32 + f8]);
#pragma unroll
        for (int nt = 0; nt < 4; ++nt) bf[nt] = *(const bf16x8*)(&Bs[(wn + nt * 16 + fr) * 32 + f8]);
#pragma unroll
        for (int mt = 0; mt < 4; ++mt)
#pragma unroll
            for (int nt = 0; nt < 4; ++nt)
                acc[mt][nt] = __builtin_amdgcn_mfma_f32_16x16x32_bf16(af[mt], bf[nt], acc[mt][nt], 0, 0, 0);
    }
    // epilogue: C/D layout col=lane&15, row=(lane>>4)*4+r  [HW-verified]
#pragma unroll
    for (int mt = 0; mt < 4; ++mt)
#pragma unroll
        for (int nt = 0; nt < 4; ++nt) {
            const size_t col = n0 + wn + nt * 16 + fr;
            const float bb = bias[col] * bias_scale;
#pragma unroll
            for (int r = 0; r < 4; ++r) {
                const size_t row = m0 + wm + mt * 16 + f4 + r;
                const float vv = acc[mt][nt][r] + bb;
                if (of32) of32[row * 1024 + col] = vv;
                else      obf[row * 1024 + col] = f2bf(vv);
            }
        }
}

// ---------------- flash attention ----------------
// grid (T/64, B*H). Block = 4 waves; wave w handles 16 q-rows. KV tiles of 64 in LDS.
// QK^T: A=Q (regs), B from K LDS rows. PV computed as O^T = V^T * P^T so both frag
// reads are contiguous ds_read_b128. O^T C/D: row=hd (lane>>4)*4+r, col=q lane&15.
__global__ __launch_bounds__(256) void k_flash(const u16* __restrict__ Q, const u16* __restrict__ K,
                                               const u16* __restrict__ Vt, u16* __restrict__ O) {
    __shared__ u16 Ks[64 * 64];
    __shared__ u16 Vs[64 * 64];
    __shared__ u16 Ps[4][16 * 64];
    __shared__ float fac_s[4][16];
    __shared__ float sum_s[4][16];
    const int tid = threadIdx.x;
    const int l = tid & 63, w = tid >> 6;
    const int bh = blockIdx.y, b = bh >> 4, h = bh & 15;
    const int qw = blockIdx.x * 64 + w * 16;
    const int fr = l & 15, f8 = (l >> 4) * 8, f4 = (l >> 4) * 4;

    // Q fragments (scale already folded into Wq/bq)
    const u16* qptr = Q + ((size_t)(b * 1024 + qw + fr)) * 1024 + h * 64 + f8;
    bf16x8 qf0 = *(const bf16x8*)qptr;
    bf16x8 qf1 = *(const bf16x8*)(qptr + 32);

    f32x4 accO[4] = {};
    float mrun[4], lrun[4];
#pragma unroll
    for (int r = 0; r < 4; ++r) { mrun[r] = -1e30f; lrun[r] = 0.f; }

    const int srow = tid >> 2, scol = (tid & 3) * 16;  // stage 16 elems/matrix/thread
    const u16* kg = K + ((size_t)(b * 1024 + srow)) * 1024 + h * 64 + scol;
    const u16* vg = Vt + ((size_t)(bh * 64 + srow)) * 1024 + scol;
    u16x8 kv0 = *(const u16x8*)kg, kv1 = *(const u16x8*)(kg + 8);
    u16x8 vv0 = *(const u16x8*)vg, vv1 = *(const u16x8*)(vg + 8);

    for (int kt0 = 0; kt0 < 1024; kt0 += 64) {
        __syncthreads();
        *(u16x8*)(&Ks[srow * 64 + scol]) = kv0;
        *(u16x8*)(&Ks[srow * 64 + scol + 8]) = kv1;
        *(u16x8*)(&Vs[srow * 64 + scol]) = vv0;
        *(u16x8*)(&Vs[srow * 64 + scol + 8]) = vv1;
        __syncthreads();
        if (kt0 + 64 < 1024) {
            kv0 = *(const u16x8*)(kg + (size_t)(kt0 + 64) * 1024);
            kv1 = *(const u16x8*)(kg + (size_t)(kt0 + 64) * 1024 + 8);
            vv0 = *(const u16x8*)(vg + kt0 + 64);
            vv1 = *(const u16x8*)(vg + kt0 + 72);
        }
        // S tiles: S[q 16][kt 64], C/D: row q = f4+r, col kt = nt*16+fr
        f32x4 s[4];
#pragma unroll
        for (int nt = 0; nt < 4; ++nt) {
            f32x4 z = {0.f, 0.f, 0.f, 0.f};
            z = __builtin_amdgcn_mfma_f32_16x16x32_bf16(qf0, *(const bf16x8*)(&Ks[(nt * 16 + fr) * 64 + f8]), z, 0, 0, 0);
            z = __builtin_amdgcn_mfma_f32_16x16x32_bf16(qf1, *(const bf16x8*)(&Ks[(nt * 16 + fr) * 64 + 32 + f8]), z, 0, 0, 0);
            s[nt] = z;
        }
        // online softmax: row reductions across the 16 lanes of each lane-group
        float tmax[4];
#pragma unroll
        for (int r = 0; r < 4; ++r) tmax[r] = fmaxf(fmaxf(s[0][r], s[1][r]), fmaxf(s[2][r], s[3][r]));
#pragma unroll
        for (int off = 1; off < 16; off <<= 1)
#pragma unroll
            for (int r = 0; r < 4; ++r) tmax[r] = fmaxf(tmax[r], __shfl_xor(tmax[r], off, 64));
        float fac[4], psum[4];
#pragma unroll
        for (int r = 0; r < 4; ++r) {
            const float mn = fmaxf(mrun[r], tmax[r]);
            fac[r] = __expf(mrun[r] - mn);
            mrun[r] = mn;
            lrun[r] *= fac[r];
            psum[r] = 0.f;
        }
#pragma unroll
        for (int nt = 0; nt < 4; ++nt)
#pragma unroll
            for (int r = 0; r < 4; ++r) {
                const float p = __expf(s[nt][r] - mrun[r]);
                psum[r] += p;
                Ps[w][(f4 + r) * 64 + nt * 16 + fr] = f2bf(p);
            }
#pragma unroll
        for (int off = 1; off < 16; off <<= 1)
#pragma unroll
            for (int r = 0; r < 4; ++r) psum[r] += __shfl_xor(psum[r], off, 64);
#pragma unroll
        for (int r = 0; r < 4; ++r) lrun[r] += psum[r];
        // broadcast rescale factor into O^T layout (indexed by q = lane&15)
        if (fr == 0) {
#pragma unroll
            for (int r = 0; r < 4; ++r) fac_s[w][f4 + r] = fac[r];
        }
        const float facT = fac_s[w][fr];
#pragma unroll
        for (int mt = 0; mt < 4; ++mt)
#pragma unroll
            for (int r = 0; r < 4; ++r) accO[mt][r] *= facT;
        // PV: O^T += V^T * P^T ; A-frag from Vs rows (hd), B-frag from Ps rows (q)
        bf16x8 pf0 = *(const bf16x8*)(&Ps[w][fr * 64 + f8]);
        bf16x8 pf1 = *(const bf16x8*)(&Ps[w][fr * 64 + 32 + f8]);
#pragma unroll
        for (int mt = 0; mt < 4; ++mt) {
            bf16x8 vf0 = *(const bf16x8*)(&Vs[(mt * 16 + fr) * 64 + f8]);
            bf16x8 vf1 = *(const bf16x8*)(&Vs[(mt * 16 + fr) * 64 + 32 + f8]);
            accO[mt] = __builtin_amdgcn_mfma_f32_16x16x32_bf16(vf0, pf0, accO[mt], 0, 0, 0);
            accO[mt] = __builtin_amdgcn_mfma_f32_16x16x32_bf16(vf1, pf1, accO[mt], 0, 0, 0);
        }
    }
    // epilogue: divide by row sums, write O[b*1024+t][h*64+hd]
    if (fr == 0) {
#pragma unroll
        for (int r = 0; r < 4; ++r) sum_s[w][f4 + r] = lrun[r];
    }
    const float inv = 1.0f / sum_s[w][fr];
#pragma unroll
    for (int mt = 0; mt < 4; ++mt) {
        u16x4 o;
#pragma unroll
        for (int r = 0; r < 4; ++r) o[r] = f2bf(accO[mt][r] * inv);
        *(u16x4*)(&O[((size_t)(b * 1024 + qw + fr)) * 1024 + h * 64 + mt * 16 + f4]) = o;
    }
}

extern "C" void kernel_launch(void* const* d_in, const int* in_sizes, int n_in,
                              void* d_out, int out_size, void* d_ws, size_t ws_size,
                              hipStream_t stream) {
    (void)in_sizes; (void)n_in; (void)out_size; (void)ws_size;
    const float* hs = (const float*)d_in[0];
    const float* Wq = (const float*)d_in[1];
    const float* bq = (const float*)d_in[2];
    const float* Wk = (const float*)d_in[3];
    const float* bk = (const float*)d_in[4];
    const float* Wv = (const float*)d_in[5];
    const float* bv = (const float*)d_in[6];
    const float* Wo = (const float*)d_in[7];
    const float* bo = (const float*)d_in[8];
    float* out = (float*)d_out;
    char* ws = (char*)d_ws;
    const size_t MB = 1024ull * 1024ull;
    u16* Xb  = (u16*)(ws);            // 16 MB (dead after V GEMM; reused as attn output Ob)
    u16* Wqt = (u16*)(ws + 16 * MB);  // 2 MB each
    u16* Wkt = (u16*)(ws + 18 * MB);
    u16* Wvt = (u16*)(ws + 20 * MB);
    u16* Wot = (u16*)(ws + 22 * MB);
    u16* Qb  = (u16*)(ws + 24 * MB);  // 16 MB
    u16* Kb  = (u16*)(ws + 40 * MB);  // 16 MB
    u16* Vb  = (u16*)(ws + 56 * MB);  // 16 MB
    u16* Vt  = (u16*)(ws + 72 * MB);  // 16 MB -> 88 MB total
    u16* Ob  = Xb;

    const float SCALE = 0.125f;  // HD^-0.5, folded into Wq and bq

    k_cvt<<<dim3(8192), dim3(256), 0, stream>>>(hs, Xb);
    k_wtrans<<<dim3(32, 32), dim3(256), 0, stream>>>(Wq, Wqt, SCALE);
    k_wtrans<<<dim3(32, 32), dim3(256), 0, stream>>>(Wk, Wkt, 1.0f);
    k_wtrans<<<dim3(32, 32), dim3(256), 0, stream>>>(Wv, Wvt, 1.0f);
    k_wtrans<<<dim3(32, 32), dim3(256), 0, stream>>>(Wo, Wot, 1.0f);
    k_gemm<<<dim3(8, 64), dim3(256), 0, stream>>>(Xb, Wqt, bq, SCALE, Qb, nullptr);
    k_gemm<<<dim3(8, 64), dim3(256), 0, stream>>>(Xb, Wkt, bk, 1.0f, Kb, nullptr);
    k_gemm<<<dim3(8, 64), dim3(256), 0, stream>>>(Xb, Wvt, bv, 1.0f, Vb, nullptr);
    k_vtrans<<<dim3(32, 32, 8), dim3(256), 0, stream>>>(Vb, Vt);
    k_flash<<<dim3(16, 128), dim3(256), 0, stream>>>(Qb, Kb, Vt, Ob);
    k_gemm<<<dim3(8, 64), dim3(256), 0, stream>>>(Ob, Wot, bo, 1.0f, nullptr, out);
}

// Round 2
// 219.984 us; speedup vs baseline: 1.3456x; 1.3456x over previous
//
#include <hip/hip_runtime.h>

typedef unsigned short u16;
typedef __attribute__((ext_vector_type(4))) float f32x4;
typedef __attribute__((ext_vector_type(8))) __bf16 bf16x8;
typedef __attribute__((ext_vector_type(4))) unsigned short u16x4;
typedef __attribute__((ext_vector_type(8))) unsigned short u16x8;

// round-to-nearest-even fp32 -> bf16
static __device__ __forceinline__ u16 f2bf(float f) {
    union { float f; unsigned u; } v; v.f = f;
    unsigned r = v.u + 0x7FFFu + ((v.u >> 16) & 1u);
    return (u16)(r >> 16);
}

// async global->LDS, 16 bytes per lane (dest must be uniform base + lane*16)
static __device__ __forceinline__ void gload16(const u16* g, u16* l) {
    __builtin_amdgcn_global_load_lds(
        (const __attribute__((address_space(1))) unsigned int*)g,
        (__attribute__((address_space(3))) unsigned int*)l, 16, 0, 0);
}

// swizzled element offset in a [rows][64] u16 tile (128B rows, XOR 16B-chunk by row&7)
#define SWZ64(row, ec) (((row) * 64) + ((((ec) ^ ((row) & 7))) << 3))

// ---------------- fp32 -> bf16 convert (4 elems/thread) ----------------
__global__ __launch_bounds__(256) void k_cvt(const float* __restrict__ in, u16* __restrict__ out) {
    size_t i = (size_t)blockIdx.x * 256 + threadIdx.x;
    float4 v = ((const float4*)in)[i];
    u16x4 o; o[0] = f2bf(v.x); o[1] = f2bf(v.y); o[2] = f2bf(v.z); o[3] = f2bf(v.w);
    *(u16x4*)(out + i * 4) = o;
}

// ---------------- W [K=1024][N=1024] fp32 -> Wt [N][K] bf16 (scaled) ----------------
__global__ __launch_bounds__(256) void k_wtrans(const float* __restrict__ W, u16* __restrict__ Wt, float scale) {
    __shared__ float tile[32][33];
    int n0 = blockIdx.x * 32, k0 = blockIdx.y * 32;
    int tid = threadIdx.x;
    int r = tid >> 3, c = (tid & 7) * 4;
    float4 v = *(const float4*)(W + (size_t)(k0 + r) * 1024 + n0 + c);
    tile[r][c] = v.x; tile[r][c + 1] = v.y; tile[r][c + 2] = v.z; tile[r][c + 3] = v.w;
    __syncthreads();
    u16x4 o;
    o[0] = f2bf(tile[c][r] * scale);
    o[1] = f2bf(tile[c + 1][r] * scale);
    o[2] = f2bf(tile[c + 2][r] * scale);
    o[3] = f2bf(tile[c + 3][r] * scale);
    *(u16x4*)(Wt + (size_t)(n0 + r) * 1024 + k0 + c) = o;
}

// ---------------- per-batch 1024x1024 bf16 transpose: Vb[b*1024+t][n] -> Vt[b*1024+n][t] ----------------
__global__ __launch_bounds__(256) void k_vtrans(const u16* __restrict__ Vb, u16* __restrict__ Vt) {
    __shared__ u16 tile[32][34];
    int z = blockIdx.z;
    int n0 = blockIdx.x * 32, t0 = blockIdx.y * 32;
    int tid = threadIdx.x;
    int r = tid >> 3, c = (tid & 7) * 4;
    u16x4 v = *(const u16x4*)(Vb + ((size_t)(z * 1024 + t0 + r)) * 1024 + n0 + c);
    tile[r][c] = v[0]; tile[r][c + 1] = v[1]; tile[r][c + 2] = v[2]; tile[r][c + 3] = v[3];
    __syncthreads();
    u16x4 o; o[0] = tile[c][r]; o[1] = tile[c + 1][r]; o[2] = tile[c + 2][r]; o[3] = tile[c + 3][r];
    *(u16x4*)(Vt + ((size_t)(z * 1024 + n0 + r)) * 1024 + t0 + c) = o;
}

// ---------------- bf16 GEMM: C[M=8192][N=1024] = A[M][1024] * Bt[N][1024]^T + bias ----------------
// 128x128 tile, BK=32, 4 waves (2x2 of 64x64), 4x4 frags/wave, global_load_lds staging (m97 structure).
__global__ __launch_bounds__(256) void k_gemm(const u16* __restrict__ A, const u16* __restrict__ Bt,
                                              const float* __restrict__ bias, float bias_scale,
                                              u16* __restrict__ obf, float* __restrict__ of32) {
    __shared__ u16 As[128 * 32];
    __shared__ u16 Bs[128 * 32];
    const int tid = threadIdx.x;
    const int l = tid & 63, w = tid >> 6;
    const int wm = (w >> 1) * 64, wn = (w & 1) * 64;
    const size_t m0 = (size_t)blockIdx.y * 128, n0 = (size_t)blockIdx.x * 128;
    const int fr = l & 15, f8 = (l >> 4) * 8, f4 = (l >> 4) * 4;
    // staging geometry: 1KB chunk j holds rows j*16..j*16+15; lane l -> row j*16+(l>>2), col (l&3)*8
    const int j0 = w * 2;
    const int srow0 = j0 * 16 + (l >> 2), srow1 = srow0 + 16;
    const int scol = (l & 3) * 8;
    const u16* Ag0 = A + (m0 + srow0) * 1024 + scol;
    const u16* Ag1 = A + (m0 + srow1) * 1024 + scol;
    const u16* Bg0 = Bt + (n0 + srow0) * 1024 + scol;
    const u16* Bg1 = Bt + (n0 + srow1) * 1024 + scol;
    u16* Al0 = As + j0 * 512 + l * 8;
    u16* Al1 = As + (j0 + 1) * 512 + l * 8;
    u16* Bl0 = Bs + j0 * 512 + l * 8;
    u16* Bl1 = Bs + (j0 + 1) * 512 + l * 8;
    f32x4 acc[4][4] = {};
    for (int kt = 0; kt < 1024; kt += 32) {
        __syncthreads();
        gload16(Ag0 + kt, Al0);
        gload16(Ag1 + kt, Al1);
        gload16(Bg0 + kt, Bl0);
        gload16(Bg1 + kt, Bl1);
        __syncthreads();
        bf16x8 af[4], bf[4];
#pragma unroll
        for (int mt = 0; mt < 4; ++mt) af[mt] = *(const bf16x8*)(&As[(wm + mt * 16 + fr) * 32 + f8]);
#pragma unroll
        for (int nt = 0; nt < 4; ++nt) bf[nt] = *(const bf16x8*)(&Bs[(wn + nt * 16 + fr) * 32 + f8]);
#pragma unroll
        for (int mt = 0; mt < 4; ++mt)
#pragma unroll
            for (int nt = 0; nt < 4; ++nt)
                acc[mt][nt] = __builtin_amdgcn_mfma_f32_16x16x32_bf16(af[mt], bf[nt], acc[mt][nt], 0, 0, 0);
    }
    // epilogue: C/D layout col=lane&15, row=(lane>>4)*4+r  [HW-verified]
#pragma unroll
    for (int mt = 0; mt < 4; ++mt)
#pragma unroll
        for (int nt = 0; nt < 4; ++nt) {
            const size_t col = n0 + wn + nt * 16 + fr;
            const float bb = bias[col] * bias_scale;
#pragma unroll
            for (int r = 0; r < 4; ++r) {
                const size_t row = m0 + wm + mt * 16 + f4 + r;
                const float vv = acc[mt][nt][r] + bb;
                if (of32) of32[row * 1024 + col] = vv;
                else      obf[row * 1024 + col] = f2bf(vv);
            }
        }
}

// ---------------- flash attention ----------------
// grid (T/64, B*H). 4 waves; wave w owns 16 q-rows. KV tiles of 64 staged via
// global_load_lds with pre-swizzled source (m173) so LDS is XOR-swizzled, all
// ds_read_b128 at bank floor. QK^T computed swapped: S^T = mfma(K,Q) so each
// lane's softmax stats are for its own q = lane&15 (2-shuffle reductions,
// vectorized swizzled P stores). PV: O^T = mfma(V^T, P).
__global__ __launch_bounds__(256) void k_flash(const u16* __restrict__ Q, const u16* __restrict__ K,
                                               const u16* __restrict__ Vt, u16* __restrict__ O) {
    __shared__ u16 Ks[64 * 64];
    __shared__ u16 Vs[64 * 64];
    __shared__ u16 Pt[4][16 * 64];
    const int tid = threadIdx.x;
    const int l = tid & 63, w = tid >> 6;
    const int bh = blockIdx.y, b = bh >> 4, h = bh & 15;
    const int qw = blockIdx.x * 64 + w * 16;
    const int fr = l & 15, f8 = (l >> 4) * 8, f4 = (l >> 4) * 4;
    const int e0 = l >> 4, e1 = (l >> 4) + 4;   // 16B-chunk indices for frag reads

    // Q fragments (SCALE folded into Wq/bq): q = qw+fr, d = f8.. / f8+32..
    const u16* qptr = Q + ((size_t)(b * 1024 + qw + fr)) * 1024 + h * 64 + f8;
    const bf16x8 qf0 = *(const bf16x8*)qptr;
    const bf16x8 qf1 = *(const bf16x8*)(qptr + 32);

    // staging geometry: chunk j (0..7) = rows j*8..j*8+7; lane l -> row j*8+(l>>3),
    // source 16B-chunk c = (l&7)^(l>>3) (pre-swizzled so LDS chunk (l&7) holds col c)
    const int jj0 = w * 2, jj1 = w * 2 + 1;
    const int sr0 = jj0 * 8 + (l >> 3), sr1 = jj1 * 8 + (l >> 3);
    const int sc = ((l & 7) ^ (l >> 3)) * 8;
    const u16* kg0 = K + ((size_t)(b * 1024 + sr0)) * 1024 + h * 64 + sc;
    const u16* kg1 = K + ((size_t)(b * 1024 + sr1)) * 1024 + h * 64 + sc;
    const u16* vg0 = Vt + ((size_t)(bh * 64 + sr0)) * 1024 + sc;
    const u16* vg1 = Vt + ((size_t)(bh * 64 + sr1)) * 1024 + sc;
    u16* kl0 = Ks + jj0 * 512 + l * 8;
    u16* kl1 = Ks + jj1 * 512 + l * 8;
    u16* vl0 = Vs + jj0 * 512 + l * 8;
    u16* vl1 = Vs + jj1 * 512 + l * 8;

    f32x4 accO[4] = {};
    float mrun = -1e30f, lrun = 0.f;   // stats for this lane's q = qw+fr

    for (int kt0 = 0; kt0 < 1024; kt0 += 64) {
        __syncthreads();
        gload16(kg0 + (size_t)kt0 * 1024, kl0);
        gload16(kg1 + (size_t)kt0 * 1024, kl1);
        gload16(vg0 + kt0, vl0);
        gload16(vg1 + kt0, vl1);
        __syncthreads();
        // S^T tiles: lane holds S[k = kt0+nt*16+f4+r][q = qw+fr]
        f32x4 s[4];
#pragma unroll
        for (int nt = 0; nt < 4; ++nt) {
            const int rk = nt * 16 + fr;
            const bf16x8 kf0 = *(const bf16x8*)(&Ks[SWZ64(rk, e0)]);
            const bf16x8 kf1 = *(const bf16x8*)(&Ks[SWZ64(rk, e1)]);
            f32x4 z = {0.f, 0.f, 0.f, 0.f};
            z = __builtin_amdgcn_mfma_f32_16x16x32_bf16(kf0, qf0, z, 0, 0, 0);
            z = __builtin_amdgcn_mfma_f32_16x16x32_bf16(kf1, qf1, z, 0, 0, 0);
            s[nt] = z;
        }
        // online softmax over k; lanes {l, l^16, l^32, l^48} share q = fr
        float tmax = s[0][0];
#pragma unroll
        for (int nt = 0; nt < 4; ++nt)
#pragma unroll
            for (int r = 0; r < 4; ++r) tmax = fmaxf(tmax, s[nt][r]);
        tmax = fmaxf(tmax, __shfl_xor(tmax, 16, 64));
        tmax = fmaxf(tmax, __shfl_xor(tmax, 32, 64));
        const float mn = fmaxf(mrun, tmax);
        const float fac = __expf(mrun - mn);
        mrun = mn;
        lrun *= fac;
        float psum = 0.f;
#pragma unroll
        for (int nt = 0; nt < 4; ++nt) {
            u16x4 pv;
#pragma unroll
            for (int r = 0; r < 4; ++r) {
                const float p = __expf(s[nt][r] - mrun);
                psum += p;
                pv[r] = f2bf(p);
            }
            // P[q=fr][k = nt*16+f4 .. +3], swizzled 8B store
            const int ec = nt * 2 + (l >> 5);
            *(u16x4*)(&Pt[w][fr * 64 + ((ec ^ (fr & 7)) << 3) + (f4 & 7)]) = pv;
        }
        psum += __shfl_xor(psum, 16, 64);
        psum += __shfl_xor(psum, 32, 64);
        lrun += psum;
#pragma unroll
        for (int mt = 0; mt < 4; ++mt)
#pragma unroll
            for (int r = 0; r < 4; ++r) accO[mt][r] *= fac;
        // PV: O^T[hd][q] += V^T[hd][k] * P[q][k]
        const bf16x8 pf0 = *(const bf16x8*)(&Pt[w][SWZ64(fr, e0)]);
        const bf16x8 pf1 = *(const bf16x8*)(&Pt[w][SWZ64(fr, e1)]);
#pragma unroll
        for (int mt = 0; mt < 4; ++mt) {
            const int rv = mt * 16 + fr;
            const bf16x8 vf0 = *(const bf16x8*)(&Vs[SWZ64(rv, e0)]);
            const bf16x8 vf1 = *(const bf16x8*)(&Vs[SWZ64(rv, e1)]);
            accO[mt] = __builtin_amdgcn_mfma_f32_16x16x32_bf16(vf0, pf0, accO[mt], 0, 0, 0);
            accO[mt] = __builtin_amdgcn_mfma_f32_16x16x32_bf16(vf1, pf1, accO[mt], 0, 0, 0);
        }
    }
    // epilogue: O[t = qw+fr][hd = mt*16+f4+r], u16x4 along hd
    const float inv = 1.0f / lrun;
#pragma unroll
    for (int mt = 0; mt < 4; ++mt) {
        u16x4 o;
#pragma unroll
        for (int r = 0; r < 4; ++r) o[r] = f2bf(accO[mt][r] * inv);
        *(u16x4*)(&O[((size_t)(b * 1024 + qw + fr)) * 1024 + h * 64 + mt * 16 + f4]) = o;
    }
}

extern "C" void kernel_launch(void* const* d_in, const int* in_sizes, int n_in,
                              void* d_out, int out_size, void* d_ws, size_t ws_size,
                              hipStream_t stream) {
    (void)in_sizes; (void)n_in; (void)out_size; (void)ws_size;
    const float* hs = (const float*)d_in[0];
    const float* Wq = (const float*)d_in[1];
    const float* bq = (const float*)d_in[2];
    const float* Wk = (const float*)d_in[3];
    const float* bk = (const float*)d_in[4];
    const float* Wv = (const float*)d_in[5];
    const float* bv = (const float*)d_in[6];
    const float* Wo = (const float*)d_in[7];
    const float* bo = (const float*)d_in[8];
    float* out = (float*)d_out;
    char* ws = (char*)d_ws;
    const size_t MB = 1024ull * 1024ull;
    u16* Xb  = (u16*)(ws);            // 16 MB (dead after V GEMM; reused as attn output Ob)
    u16* Wqt = (u16*)(ws + 16 * MB);  // 2 MB each
    u16* Wkt = (u16*)(ws + 18 * MB);
    u16* Wvt = (u16*)(ws + 20 * MB);
    u16* Wot = (u16*)(ws + 22 * MB);
    u16* Qb  = (u16*)(ws + 24 * MB);  // 16 MB
    u16* Kb  = (u16*)(ws + 40 * MB);  // 16 MB
    u16* Vb  = (u16*)(ws + 56 * MB);  // 16 MB
    u16* Vt  = (u16*)(ws + 72 * MB);  // 16 MB -> 88 MB total
    u16* Ob  = Xb;

    const float SCALE = 0.125f;  // HD^-0.5, folded into Wq and bq

    k_cvt<<<dim3(8192), dim3(256), 0, stream>>>(hs, Xb);
    k_wtrans<<<dim3(32, 32), dim3(256), 0, stream>>>(Wq, Wqt, SCALE);
    k_wtrans<<<dim3(32, 32), dim3(256), 0, stream>>>(Wk, Wkt, 1.0f);
    k_wtrans<<<dim3(32, 32), dim3(256), 0, stream>>>(Wv, Wvt, 1.0f);
    k_wtrans<<<dim3(32, 32), dim3(256), 0, stream>>>(Wo, Wot, 1.0f);
    k_gemm<<<dim3(8, 64), dim3(256), 0, stream>>>(Xb, Wqt, bq, SCALE, Qb, nullptr);
    k_gemm<<<dim3(8, 64), dim3(256), 0, stream>>>(Xb, Wkt, bk, 1.0f, Kb, nullptr);
    k_gemm<<<dim3(8, 64), dim3(256), 0, stream>>>(Xb, Wvt, bv, 1.0f, Vb, nullptr);
    k_vtrans<<<dim3(32, 32, 8), dim3(256), 0, stream>>>(Vb, Vt);
    k_flash<<<dim3(16, 128), dim3(256), 0, stream>>>(Qb, Kb, Vt, Ob);
    k_gemm<<<dim3(8, 64), dim3(256), 0, stream>>>(Ob, Wot, bo, 1.0f, nullptr, out);
}

// Round 3
// 206.684 us; speedup vs baseline: 1.4321x; 1.0643x over previous
//
#include <hip/hip_runtime.h>

typedef unsigned short u16;
typedef __attribute__((ext_vector_type(4))) float f32x4;
typedef __attribute__((ext_vector_type(8))) __bf16 bf16x8;
typedef __attribute__((ext_vector_type(4))) __bf16 bf16x4;
typedef __attribute__((ext_vector_type(4))) unsigned short u16x4;
typedef __attribute__((ext_vector_type(8))) unsigned short u16x8;

// round-to-nearest-even fp32 -> bf16 (used in epilogues / converts)
static __device__ __forceinline__ u16 f2bf(float f) {
    union { float f; unsigned u; } v; v.f = f;
    unsigned r = v.u + 0x7FFFu + ((v.u >> 16) & 1u);
    return (u16)(r >> 16);
}

// v_exp_f32: D = 2^x
static __device__ __forceinline__ float exp2f_fast(float x) {
    float r; asm("v_exp_f32 %0, %1" : "=v"(r) : "v"(x)); return r;
}

// async global->LDS, 16 bytes per lane (dest must be uniform base + lane*16)
static __device__ __forceinline__ void gload16(const u16* g, u16* l) {
    __builtin_amdgcn_global_load_lds(
        (const __attribute__((address_space(1))) unsigned int*)g,
        (__attribute__((address_space(3))) unsigned int*)l, 16, 0, 0);
}

// swizzled element offset in a [rows][64] u16 tile (128B rows, XOR 16B-chunk by row&7)
#define SWZ64(row, ec) (((row) * 64) + ((((ec) ^ ((row) & 7))) << 3))

// ---------------- fp32 -> bf16 convert (4 elems/thread) ----------------
__global__ __launch_bounds__(256) void k_cvt(const float* __restrict__ in, u16* __restrict__ out) {
    size_t i = (size_t)blockIdx.x * 256 + threadIdx.x;
    float4 v = ((const float4*)in)[i];
    u16x4 o; o[0] = f2bf(v.x); o[1] = f2bf(v.y); o[2] = f2bf(v.z); o[3] = f2bf(v.w);
    *(u16x4*)(out + i * 4) = o;
}

// ---------------- W [K=1024][N=1024] fp32 -> Wt [N][K] bf16 (scaled) ----------------
__global__ __launch_bounds__(256) void k_wtrans(const float* __restrict__ W, u16* __restrict__ Wt, float scale) {
    __shared__ float tile[32][33];
    int n0 = blockIdx.x * 32, k0 = blockIdx.y * 32;
    int tid = threadIdx.x;
    int r = tid >> 3, c = (tid & 7) * 4;
    float4 v = *(const float4*)(W + (size_t)(k0 + r) * 1024 + n0 + c);
    tile[r][c] = v.x; tile[r][c + 1] = v.y; tile[r][c + 2] = v.z; tile[r][c + 3] = v.w;
    __syncthreads();
    u16x4 o;
    o[0] = f2bf(tile[c][r] * scale);
    o[1] = f2bf(tile[c + 1][r] * scale);
    o[2] = f2bf(tile[c + 2][r] * scale);
    o[3] = f2bf(tile[c + 3][r] * scale);
    *(u16x4*)(Wt + (size_t)(n0 + r) * 1024 + k0 + c) = o;
}

// ---------------- per-batch 1024x1024 bf16 transpose: Vb[b*1024+t][n] -> Vt[b*1024+n][t] ----------------
__global__ __launch_bounds__(256) void k_vtrans(const u16* __restrict__ Vb, u16* __restrict__ Vt) {
    __shared__ u16 tile[32][34];
    int z = blockIdx.z;
    int n0 = blockIdx.x * 32, t0 = blockIdx.y * 32;
    int tid = threadIdx.x;
    int r = tid >> 3, c = (tid & 7) * 4;
    u16x4 v = *(const u16x4*)(Vb + ((size_t)(z * 1024 + t0 + r)) * 1024 + n0 + c);
    tile[r][c] = v[0]; tile[r][c + 1] = v[1]; tile[r][c + 2] = v[2]; tile[r][c + 3] = v[3];
    __syncthreads();
    u16x4 o; o[0] = tile[c][r]; o[1] = tile[c + 1][r]; o[2] = tile[c + 2][r]; o[3] = tile[c + 3][r];
    *(u16x4*)(Vt + ((size_t)(z * 1024 + n0 + r)) * 1024 + t0 + c) = o;
}

// ---------------- bf16 GEMM: C[M=8192][N=1024] = A[M][1024] * Bt[N][1024]^T + bias ----------------
// 128x128 tile, BK=32, 4 waves (2x2 of 64x64), 4x4 frags/wave, global_load_lds staging (m97 structure).
__global__ __launch_bounds__(256) void k_gemm(const u16* __restrict__ A, const u16* __restrict__ Bt,
                                              const float* __restrict__ bias, float bias_scale,
                                              u16* __restrict__ obf, float* __restrict__ of32) {
    __shared__ u16 As[128 * 32];
    __shared__ u16 Bs[128 * 32];
    const int tid = threadIdx.x;
    const int l = tid & 63, w = tid >> 6;
    const int wm = (w >> 1) * 64, wn = (w & 1) * 64;
    const size_t m0 = (size_t)blockIdx.y * 128, n0 = (size_t)blockIdx.x * 128;
    const int fr = l & 15, f8 = (l >> 4) * 8, f4 = (l >> 4) * 4;
    // staging geometry: 1KB chunk j holds rows j*16..j*16+15; lane l -> row j*16+(l>>2), col (l&3)*8
    const int j0 = w * 2;
    const int srow0 = j0 * 16 + (l >> 2), srow1 = srow0 + 16;
    const int scol = (l & 3) * 8;
    const u16* Ag0 = A + (m0 + srow0) * 1024 + scol;
    const u16* Ag1 = A + (m0 + srow1) * 1024 + scol;
    const u16* Bg0 = Bt + (n0 + srow0) * 1024 + scol;
    const u16* Bg1 = Bt + (n0 + srow1) * 1024 + scol;
    u16* Al0 = As + j0 * 512 + l * 8;
    u16* Al1 = As + (j0 + 1) * 512 + l * 8;
    u16* Bl0 = Bs + j0 * 512 + l * 8;
    u16* Bl1 = Bs + (j0 + 1) * 512 + l * 8;
    f32x4 acc[4][4] = {};
    for (int kt = 0; kt < 1024; kt += 32) {
        __syncthreads();
        gload16(Ag0 + kt, Al0);
        gload16(Ag1 + kt, Al1);
        gload16(Bg0 + kt, Bl0);
        gload16(Bg1 + kt, Bl1);
        __syncthreads();
        bf16x8 af[4], bf[4];
#pragma unroll
        for (int mt = 0; mt < 4; ++mt) af[mt] = *(const bf16x8*)(&As[(wm + mt * 16 + fr) * 32 + f8]);
#pragma unroll
        for (int nt = 0; nt < 4; ++nt) bf[nt] = *(const bf16x8*)(&Bs[(wn + nt * 16 + fr) * 32 + f8]);
#pragma unroll
        for (int mt = 0; mt < 4; ++mt)
#pragma unroll
            for (int nt = 0; nt < 4; ++nt)
                acc[mt][nt] = __builtin_amdgcn_mfma_f32_16x16x32_bf16(af[mt], bf[nt], acc[mt][nt], 0, 0, 0);
    }
    // epilogue: C/D layout col=lane&15, row=(lane>>4)*4+r  [HW-verified]
#pragma unroll
    for (int mt = 0; mt < 4; ++mt)
#pragma unroll
        for (int nt = 0; nt < 4; ++nt) {
            const size_t col = n0 + wn + nt * 16 + fr;
            const float bb = bias[col] * bias_scale;
#pragma unroll
            for (int r = 0; r < 4; ++r) {
                const size_t row = m0 + wm + mt * 16 + f4 + r;
                const float vv = acc[mt][nt][r] + bb;
                if (of32) of32[row * 1024 + col] = vv;
                else      obf[row * 1024 + col] = f2bf(vv);
            }
        }
}

// ---------------- flash attention ----------------
// 1D grid 1024 blocks (XCD-bijective swizzle: each XCD owns 16 (b,h) slices -> K/V L2-resident).
// 4 waves; each wave owns 32 q-rows as two groups A (qw+fr) and B (qw+16+fr).
// Swapped QK^T (S^T = mfma(K, Q)) with C-init = -m (log2-domain, LOG2E folded into Wq/bq):
// steady state p = v_exp(s) with zero subs. T13 defer-rescale via wave-uniform __any.
// PV feeds P directly from registers as the B-fragment (k-permutation invariance);
// V A-fragments read with the matching permuted k-order (2x b64 per k-block).
__global__ __launch_bounds__(256, 3) void k_flash(const u16* __restrict__ Q, const u16* __restrict__ K,
                                                  const u16* __restrict__ Vt, u16* __restrict__ O) {
    __shared__ u16 Ks[64 * 64];
    __shared__ u16 Vs[64 * 64];
    const int tid = threadIdx.x;
    const int l = tid & 63, w = tid >> 6;
    const int id = blockIdx.x;
    const int swz = (id & 7) * 128 + (id >> 3);      // bijective XCD swizzle (1024 % 8 == 0)
    const int bh = swz >> 3, qt = swz & 7;
    const int b = bh >> 4, h = bh & 15;
    const int qw = qt * 128 + w * 32;
    const int fr = l & 15, gg = l >> 4, f4 = gg * 4, f8 = gg * 8;

    // Q fragments (SCALE*LOG2E folded into Wq/bq)
    const u16* qpA = Q + ((size_t)(b * 1024 + qw + fr)) * 1024 + h * 64 + f8;
    const u16* qpB = qpA + 16 * 1024;
    const bf16x8 qA0 = *(const bf16x8*)qpA;
    const bf16x8 qA1 = *(const bf16x8*)(qpA + 32);
    const bf16x8 qB0 = *(const bf16x8*)qpB;
    const bf16x8 qB1 = *(const bf16x8*)(qpB + 32);

    // staging geometry: chunk j (0..7) = rows j*8..j*8+7; lane l -> row j*8+(l>>3),
    // source 16B-chunk (l&7)^(l>>3) (pre-swizzled so LDS is XOR-swizzled, dest linear)
    const int jj0 = w * 2, jj1 = w * 2 + 1;
    const int sr0 = jj0 * 8 + (l >> 3), sr1 = jj1 * 8 + (l >> 3);
    const int sc = ((l & 7) ^ (l >> 3)) * 8;
    const u16* kg0 = K + ((size_t)(b * 1024 + sr0)) * 1024 + h * 64 + sc;
    const u16* kg1 = K + ((size_t)(b * 1024 + sr1)) * 1024 + h * 64 + sc;
    const u16* vg0 = Vt + ((size_t)(bh * 64 + sr0)) * 1024 + sc;
    const u16* vg1 = Vt + ((size_t)(bh * 64 + sr1)) * 1024 + sc;
    u16* kl0 = Ks + jj0 * 512 + l * 8;
    u16* kl1 = Ks + jj1 * 512 + l * 8;
    u16* vl0 = Vs + jj0 * 512 + l * 8;
    u16* vl1 = Vs + jj1 * 512 + l * 8;

    f32x4 oA[4] = {}, oB[4] = {};
    float mA = 0.f, lA = 0.f, mB = 0.f, lB = 0.f;  // log2-domain running max, linear sum

    for (int kt0 = 0; kt0 < 1024; kt0 += 64) {
        __syncthreads();
        gload16(kg0 + (size_t)kt0 * 1024, kl0);
        gload16(kg1 + (size_t)kt0 * 1024, kl1);
        gload16(vg0 + kt0, vl0);
        gload16(vg1 + kt0, vl1);
        __syncthreads();

        // S^T - m: lane holds (S[k = kt0+nt*16+f4+r][q] - m) for q = qw(+16)+fr
        f32x4 sA[4], sB[4];
#pragma unroll
        for (int nt = 0; nt < 4; ++nt) {
            const int rk = nt * 16 + fr;
            const bf16x8 kf0 = *(const bf16x8*)(&Ks[SWZ64(rk, gg)]);
            const bf16x8 kf1 = *(const bf16x8*)(&Ks[SWZ64(rk, gg + 4)]);
            f32x4 z = {-mA, -mA, -mA, -mA};
            z = __builtin_amdgcn_mfma_f32_16x16x32_bf16(kf0, qA0, z, 0, 0, 0);
            z = __builtin_amdgcn_mfma_f32_16x16x32_bf16(kf1, qA1, z, 0, 0, 0);
            sA[nt] = z;
            f32x4 y = {-mB, -mB, -mB, -mB};
            y = __builtin_amdgcn_mfma_f32_16x16x32_bf16(kf0, qB0, y, 0, 0, 0);
            y = __builtin_amdgcn_mfma_f32_16x16x32_bf16(kf1, qB1, y, 0, 0, 0);
            sB[nt] = y;
        }

        bf16x4 pA[4], pB[4];
        // ---- softmax group A ----
        {
            float tmax = sA[0][0];
#pragma unroll
            for (int nt = 0; nt < 4; ++nt)
#pragma unroll
                for (int r = 0; r < 4; ++r) tmax = fmaxf(tmax, sA[nt][r]);
            tmax = fmaxf(tmax, __shfl_xor(tmax, 16, 64));
            tmax = fmaxf(tmax, __shfl_xor(tmax, 32, 64));
            float ps = 0.f;
            if (__any(tmax > 11.0f)) {
                const float d = fmaxf(tmax, 0.f);
                const float fac = exp2f_fast(-d);
                mA += d; lA *= fac;
#pragma unroll
                for (int mt = 0; mt < 4; ++mt)
#pragma unroll
                    for (int r = 0; r < 4; ++r) oA[mt][r] *= fac;
#pragma unroll
                for (int nt = 0; nt < 4; ++nt)
#pragma unroll
                    for (int r = 0; r < 4; ++r) {
                        const float p = exp2f_fast(sA[nt][r] - d);
                        ps += p; pA[nt][r] = (__bf16)p;
                    }
            } else {
#pragma unroll
                for (int nt = 0; nt < 4; ++nt)
#pragma unroll
                    for (int r = 0; r < 4; ++r) {
                        const float p = exp2f_fast(sA[nt][r]);
                        ps += p; pA[nt][r] = (__bf16)p;
                    }
            }
            ps += __shfl_xor(ps, 16, 64);
            ps += __shfl_xor(ps, 32, 64);
            lA += ps;
        }
        // ---- softmax group B ----
        {
            float tmax = sB[0][0];
#pragma unroll
            for (int nt = 0; nt < 4; ++nt)
#pragma unroll
                for (int r = 0; r < 4; ++r) tmax = fmaxf(tmax, sB[nt][r]);
            tmax = fmaxf(tmax, __shfl_xor(tmax, 16, 64));
            tmax = fmaxf(tmax, __shfl_xor(tmax, 32, 64));
            float ps = 0.f;
            if (__any(tmax > 11.0f)) {
                const float d = fmaxf(tmax, 0.f);
                const float fac = exp2f_fast(-d);
                mB += d; lB *= fac;
#pragma unroll
                for (int mt = 0; mt < 4; ++mt)
#pragma unroll
                    for (int r = 0; r < 4; ++r) oB[mt][r] *= fac;
#pragma unroll
                for (int nt = 0; nt < 4; ++nt)
#pragma unroll
                    for (int r = 0; r < 4; ++r) {
                        const float p = exp2f_fast(sB[nt][r] - d);
                        ps += p; pB[nt][r] = (__bf16)p;
                    }
            } else {
#pragma unroll
                for (int nt = 0; nt < 4; ++nt)
#pragma unroll
                    for (int r = 0; r < 4; ++r) {
                        const float p = exp2f_fast(sB[nt][r]);
                        ps += p; pB[nt][r] = (__bf16)p;
                    }
            }
            ps += __shfl_xor(ps, 16, 64);
            ps += __shfl_xor(ps, 32, 64);
            lB += ps;
        }

        // B-fragments straight from registers: reg j of k-block0 = p at time (j>>2)*16 + gg*4 + (j&3)
        const bf16x8 BA0 = __builtin_shufflevector(pA[0], pA[1], 0, 1, 2, 3, 4, 5, 6, 7);
        const bf16x8 BA1 = __builtin_shufflevector(pA[2], pA[3], 0, 1, 2, 3, 4, 5, 6, 7);
        const bf16x8 BB0 = __builtin_shufflevector(pB[0], pB[1], 0, 1, 2, 3, 4, 5, 6, 7);
        const bf16x8 BB1 = __builtin_shufflevector(pB[2], pB[3], 0, 1, 2, 3, 4, 5, 6, 7);

        // PV: A-frag reg j = V^T[hd][(j>>2)*16 + gg*4 + (j&3)] (+32 for k-block1)
        const int e0 = gg >> 1, hf = (gg & 1) * 4;
#pragma unroll
        for (int mt = 0; mt < 4; ++mt) {
            const int rv = mt * 16 + fr;
            const int rs = rv & 7, rb = rv * 64;
            const bf16x4 v0 = *(const bf16x4*)(&Vs[rb + (((e0    ) ^ rs) << 3) + hf]);
            const bf16x4 v1 = *(const bf16x4*)(&Vs[rb + (((e0 + 2) ^ rs) << 3) + hf]);
            const bf16x4 v2 = *(const bf16x4*)(&Vs[rb + (((e0 + 4) ^ rs) << 3) + hf]);
            const bf16x4 v3 = *(const bf16x4*)(&Vs[rb + (((e0 + 6) ^ rs) << 3) + hf]);
            const bf16x8 vk0 = __builtin_shufflevector(v0, v1, 0, 1, 2, 3, 4, 5, 6, 7);
            const bf16x8 vk1 = __builtin_shufflevector(v2, v3, 0, 1, 2, 3, 4, 5, 6, 7);
            oA[mt] = __builtin_amdgcn_mfma_f32_16x16x32_bf16(vk0, BA0, oA[mt], 0, 0, 0);
            oA[mt] = __builtin_amdgcn_mfma_f32_16x16x32_bf16(vk1, BA1, oA[mt], 0, 0, 0);
            oB[mt] = __builtin_amdgcn_mfma_f32_16x16x32_bf16(vk0, BB0, oB[mt], 0, 0, 0);
            oB[mt] = __builtin_amdgcn_mfma_f32_16x16x32_bf16(vk1, BB1, oB[mt], 0, 0, 0);
        }
    }
    // epilogue: O[t][h*64 + mt*16 + f4 + r]
    const float ivA = 1.0f / lA, ivB = 1.0f / lB;
    u16* opA = O + ((size_t)(b * 1024 + qw + fr)) * 1024 + h * 64;
    u16* opB = opA + 16 * 1024;
#pragma unroll
    for (int mt = 0; mt < 4; ++mt) {
        u16x4 oa, ob;
#pragma unroll
        for (int r = 0; r < 4; ++r) { oa[r] = f2bf(oA[mt][r] * ivA); ob[r] = f2bf(oB[mt][r] * ivB); }
        *(u16x4*)(opA + mt * 16 + f4) = oa;
        *(u16x4*)(opB + mt * 16 + f4) = ob;
    }
}

extern "C" void kernel_launch(void* const* d_in, const int* in_sizes, int n_in,
                              void* d_out, int out_size, void* d_ws, size_t ws_size,
                              hipStream_t stream) {
    (void)in_sizes; (void)n_in; (void)out_size; (void)ws_size;
    const float* hs = (const float*)d_in[0];
    const float* Wq = (const float*)d_in[1];
    const float* bq = (const float*)d_in[2];
    const float* Wk = (const float*)d_in[3];
    const float* bk = (const float*)d_in[4];
    const float* Wv = (const float*)d_in[5];
    const float* bv = (const float*)d_in[6];
    const float* Wo = (const float*)d_in[7];
    const float* bo = (const float*)d_in[8];
    float* out = (float*)d_out;
    char* ws = (char*)d_ws;
    const size_t MB = 1024ull * 1024ull;
    u16* Xb  = (u16*)(ws);            // 16 MB (dead after V GEMM; reused as attn output Ob)
    u16* Wqt = (u16*)(ws + 16 * MB);  // 2 MB each
    u16* Wkt = (u16*)(ws + 18 * MB);
    u16* Wvt = (u16*)(ws + 20 * MB);
    u16* Wot = (u16*)(ws + 22 * MB);
    u16* Qb  = (u16*)(ws + 24 * MB);  // 16 MB
    u16* Kb  = (u16*)(ws + 40 * MB);  // 16 MB
    u16* Vb  = (u16*)(ws + 56 * MB);  // 16 MB
    u16* Vt  = (u16*)(ws + 72 * MB);  // 16 MB -> 88 MB total
    u16* Ob  = Xb;

    // HD^-0.5 * log2(e) folded into Wq and bq (softmax runs in log2 domain)
    const float SCALE_Q = 0.125f * 1.4426950408889634f;

    k_cvt<<<dim3(8192), dim3(256), 0, stream>>>(hs, Xb);
    k_wtrans<<<dim3(32, 32), dim3(256), 0, stream>>>(Wq, Wqt, SCALE_Q);
    k_wtrans<<<dim3(32, 32), dim3(256), 0, stream>>>(Wk, Wkt, 1.0f);
    k_wtrans<<<dim3(32, 32), dim3(256), 0, stream>>>(Wv, Wvt, 1.0f);
    k_wtrans<<<dim3(32, 32), dim3(256), 0, stream>>>(Wo, Wot, 1.0f);
    k_gemm<<<dim3(8, 64), dim3(256), 0, stream>>>(Xb, Wqt, bq, SCALE_Q, Qb, nullptr);
    k_gemm<<<dim3(8, 64), dim3(256), 0, stream>>>(Xb, Wkt, bk, 1.0f, Kb, nullptr);
    k_gemm<<<dim3(8, 64), dim3(256), 0, stream>>>(Xb, Wvt, bv, 1.0f, Vb, nullptr);
    k_vtrans<<<dim3(32, 32, 8), dim3(256), 0, stream>>>(Vb, Vt);
    k_flash<<<dim3(1024), dim3(256), 0, stream>>>(Qb, Kb, Vt, Ob);
    k_gemm<<<dim3(8, 64), dim3(256), 0, stream>>>(Ob, Wot, bo, 1.0f, nullptr, out);
}